// Round 4
// baseline (501.510 us; speedup 1.0000x reference)
//
#include <hip/hip_runtime.h>

#define D 128
#define NN 100000

typedef __attribute__((ext_vector_type(8))) short short8;
typedef __attribute__((ext_vector_type(4))) float floatx4;

__device__ inline unsigned short bf16_rne(float f) {
    unsigned int u = __float_as_uint(f);
    u += 0x7fff + ((u >> 16) & 1);
    return (unsigned short)(u >> 16);
}
__device__ inline float bflo(unsigned int u) { return __uint_as_float(u << 16); }
__device__ inline float bfhi(unsigned int u) { return __uint_as_float(u & 0xffff0000u); }

// ---------------------------------------------------------------------------
// CSR build: hist (+rank) -> scan -> streaming fill (no atomics in fill)
// ---------------------------------------------------------------------------
__global__ __launch_bounds__(256) void hist_rank_kernel(
    const int* __restrict__ dst, int* __restrict__ counts,
    int* __restrict__ rank, int E)
{
    int e = blockIdx.x * 256 + threadIdx.x;
    if (e < E) rank[e] = atomicAdd(&counts[dst[e]], 1);
}

__global__ __launch_bounds__(256) void scan1_kernel(
    const int* __restrict__ counts, int* __restrict__ row_ptr,
    int* __restrict__ blockSums, int N)
{
    __shared__ int sd[256];
    int t = threadIdx.x;
    int base = blockIdx.x * 1024;
    int v[4]; int tot = 0;
#pragma unroll
    for (int i = 0; i < 4; i++) {
        int idx = base + t * 4 + i;
        v[i] = (idx < N) ? counts[idx] : 0;
        tot += v[i];
    }
    sd[t] = tot; __syncthreads();
    for (int off = 1; off < 256; off <<= 1) {
        int x = (t >= off) ? sd[t - off] : 0;
        __syncthreads();
        sd[t] += x;
        __syncthreads();
    }
    int excl = sd[t] - tot;
    if (t == 255) blockSums[blockIdx.x] = sd[255];
    int run = excl;
#pragma unroll
    for (int i = 0; i < 4; i++) {
        int idx = base + t * 4 + i;
        if (idx < N) row_ptr[idx] = run;
        run += v[i];
    }
}

__global__ __launch_bounds__(256) void scan2_kernel(
    const int* __restrict__ blockSums, int* __restrict__ blockOffs, int nb)
{
    __shared__ int sd[256];
    int t = threadIdx.x;
    int val = (t < nb) ? blockSums[t] : 0;
    sd[t] = val; __syncthreads();
    for (int off = 1; off < 256; off <<= 1) {
        int x = (t >= off) ? sd[t - off] : 0;
        __syncthreads();
        sd[t] += x;
        __syncthreads();
    }
    if (t < nb) blockOffs[t] = sd[t] - val;
}

__global__ __launch_bounds__(256) void scan3_kernel(
    int* __restrict__ row_ptr, const int* __restrict__ blockOffs, int N, int E)
{
    int i = blockIdx.x * 256 + threadIdx.x;
    if (i < N) row_ptr[i] += blockOffs[i >> 10];
    if (i == N) row_ptr[N] = E;
}

__global__ __launch_bounds__(256) void fill_stream_kernel(
    const int* __restrict__ src, const int* __restrict__ dst,
    const int* __restrict__ row_ptr, const int* __restrict__ rank,
    int* __restrict__ col, int E)
{
    int e = blockIdx.x * 256 + threadIdx.x;
    if (e >= E) return;
    col[row_ptr[dst[e]] + rank[e]] = src[e];
}

// ---------------------------------------------------------------------------
// fp32 -> bf16 conversions
// ---------------------------------------------------------------------------
__global__ __launch_bounds__(256) void cvt_bf16_kernel(
    const float* __restrict__ in, unsigned short* __restrict__ out, int n4)
{
    int i = blockIdx.x * 256 + threadIdx.x;
    if (i >= n4) return;
    float4 v = *(const float4*)(in + (size_t)i * 4);
    unsigned short u[4] = { bf16_rne(v.x), bf16_rne(v.y), bf16_rne(v.z), bf16_rne(v.w) };
    *(uint2*)(out + (size_t)i * 4) = *(uint2*)u;
}

// Wt[layer][n][k] bf16: k<128 -> Ws[k][n], else Wn[k-128][n]
__global__ __launch_bounds__(256) void build_wt_kernel(
    const float* __restrict__ Ws0, const float* __restrict__ Wn0,
    const float* __restrict__ Ws1, const float* __restrict__ Wn1,
    unsigned short* __restrict__ wt0, unsigned short* __restrict__ wt1)
{
    int i = blockIdx.x * 256 + threadIdx.x;   // 0 .. 65535
    int layer = i >> 15;
    int r = i & 32767;
    int n = r >> 8;
    int k = r & 255;
    const float* Ws = layer ? Ws1 : Ws0;
    const float* Wn = layer ? Wn1 : Wn0;
    float v = (k < 128) ? Ws[(size_t)k * 128 + n] : Wn[(size_t)(k - 128) * 128 + n];
    unsigned short* wt = layer ? wt1 : wt0;
    wt[(size_t)n * 256 + k] = bf16_rne(v);
}

// ---------------------------------------------------------------------------
// Fused layer: gather (mean of neighbor rows) + dual-GEMM MFMA + epilogue.
// Block = 256 thr = 4 waves; block owns 64 rows; wave w owns rows w*16..+15.
// Gather: 4 node-groups/wave (group = quad), 16 lanes x uint4 (8 bf16) per row.
// Result stored in LDS sMsg in MFMA A-fragment order (wave-private -> NO
// __syncthreads anywhere in this kernel).
// MFMA: 16x16x32_bf16, K=256 (k<128: self from A16 global; k>=128: sMsg).
// B-fragments read directly from global Wt (64KB, L2-resident) -- no LDS W.
// ---------------------------------------------------------------------------
__global__ __launch_bounds__(256) void fused_layer_kernel(
    const unsigned short* __restrict__ A16, const int* __restrict__ row_ptr,
    const int* __restrict__ col, const int* __restrict__ in_deg,
    const unsigned short* __restrict__ Wt,   // [128 n][256 k] bf16
    const float* __restrict__ bias,
    const float* __restrict__ ln_g, const float* __restrict__ ln_b,
    unsigned short* __restrict__ Out16, float* __restrict__ Out32,
    int N, int do_ln)
{
    // sMsg layout (ushort idx): ((wave*16 + kc*4 + quad)*16 + row)*8 + j
    // consumer (a-frag) reads are 1KB-contiguous per wave -> conflict-free
    __shared__ unsigned short sMsg[4 * 16 * 16 * 8];   // 16 KB

    const int tid  = threadIdx.x;
    const int wave = tid >> 6;
    const int lane = tid & 63;
    const int quad = lane >> 4;
    const int ln16 = lane & 15;
    const int wrow0 = blockIdx.x * 64 + wave * 16;

    // ---- Phase 1: gather 16 nodes (4 iterations x 4 groups) ----
    const size_t lo = (size_t)ln16 * 8;
#pragma unroll
    for (int t = 0; t < 4; t++) {
        const int r = t * 4 + quad;          // node-local row 0..15
        const int node = wrow0 + r;
        float f[8] = {0.f,0.f,0.f,0.f,0.f,0.f,0.f,0.f};
        if (node < N) {
            int beg = row_ptr[node];
            int end = row_ptr[node + 1];
            int j = beg;
            for (; j + 2 <= end; j += 2) {
                int c0 = col[j], c1 = col[j + 1];
                uint4 u0 = *(const uint4*)(A16 + (size_t)c0 * D + lo);
                uint4 u1 = *(const uint4*)(A16 + (size_t)c1 * D + lo);
                f[0] += bflo(u0.x); f[1] += bfhi(u0.x);
                f[2] += bflo(u0.y); f[3] += bfhi(u0.y);
                f[4] += bflo(u0.z); f[5] += bfhi(u0.z);
                f[6] += bflo(u0.w); f[7] += bfhi(u0.w);
                f[0] += bflo(u1.x); f[1] += bfhi(u1.x);
                f[2] += bflo(u1.y); f[3] += bfhi(u1.y);
                f[4] += bflo(u1.z); f[5] += bfhi(u1.z);
                f[6] += bflo(u1.w); f[7] += bfhi(u1.w);
            }
            if (j < end) {
                int c0 = col[j];
                uint4 u0 = *(const uint4*)(A16 + (size_t)c0 * D + lo);
                f[0] += bflo(u0.x); f[1] += bfhi(u0.x);
                f[2] += bflo(u0.y); f[3] += bfhi(u0.y);
                f[4] += bflo(u0.z); f[5] += bfhi(u0.z);
                f[6] += bflo(u0.w); f[7] += bfhi(u0.w);
            }
            int dg = in_deg[node];
            float invd = 1.f / (float)(dg > 1 ? dg : 1);
#pragma unroll
            for (int i = 0; i < 8; i++) f[i] *= invd;
        }
        unsigned short us[8];
#pragma unroll
        for (int i = 0; i < 8; i++) us[i] = bf16_rne(f[i]);
        // producer idx: ((wave*16 + ln16)*16 + r)*8   (ln16 == kc*4+quad slot)
        *(uint4*)&sMsg[(((size_t)wave * 16 + ln16) * 16 + r) * 8] = *(const uint4*)us;
    }

    // ---- Phase 2: load all 8 A-fragments, then MFMA over K=256 ----
    short8 afr[8];
    {
        const int arow = wrow0 + ln16;
        const bool arv = arow < N;
#pragma unroll
        for (int kc = 0; kc < 4; kc++) {
            if (arv) afr[kc] = *(const short8*)(A16 + (size_t)arow * D + kc * 32 + quad * 8);
            else     afr[kc] = (short8){0,0,0,0,0,0,0,0};
        }
#pragma unroll
        for (int kc = 0; kc < 4; kc++) {
            afr[4 + kc] = *(const short8*)&sMsg[(((size_t)wave * 16 + kc * 4 + quad) * 16 + ln16) * 8];
        }
    }

    floatx4 acc[8];
#pragma unroll
    for (int ct = 0; ct < 8; ct++) acc[ct] = (floatx4){0.f, 0.f, 0.f, 0.f};

#pragma unroll
    for (int kc = 0; kc < 8; kc++) {
#pragma unroll
        for (int ct = 0; ct < 8; ct++) {
            short8 b = *(const short8*)(Wt + ((size_t)(ct * 16 + ln16)) * 256 + kc * 32 + quad * 8);
            acc[ct] = __builtin_amdgcn_mfma_f32_16x16x32_bf16(afr[kc], b, acc[ct], 0, 0, 0);
        }
    }

    // ---- Epilogue: bias (+ LN + ReLU) ----
    float bb[8];
#pragma unroll
    for (int ct = 0; ct < 8; ct++) bb[ct] = bias[ct * 16 + ln16];

    float v[8][4];
#pragma unroll
    for (int ct = 0; ct < 8; ct++)
#pragma unroll
        for (int r = 0; r < 4; r++) v[ct][r] = acc[ct][r] + bb[ct];

    if (do_ln) {
        float gg[8], be[8];
#pragma unroll
        for (int ct = 0; ct < 8; ct++) {
            gg[ct] = ln_g[ct * 16 + ln16];
            be[ct] = ln_b[ct * 16 + ln16];
        }
        float s[4] = {0.f,0.f,0.f,0.f}, s2[4] = {0.f,0.f,0.f,0.f};
#pragma unroll
        for (int ct = 0; ct < 8; ct++)
#pragma unroll
            for (int r = 0; r < 4; r++) { s[r] += v[ct][r]; s2[r] += v[ct][r] * v[ct][r]; }
#pragma unroll
        for (int off = 1; off < 16; off <<= 1) {
#pragma unroll
            for (int r = 0; r < 4; r++) {
                s[r]  += __shfl_xor(s[r],  off);
                s2[r] += __shfl_xor(s2[r], off);
            }
        }
#pragma unroll
        for (int r = 0; r < 4; r++) {
            float mean = s[r] * (1.f / 128.f);
            float var  = s2[r] * (1.f / 128.f) - mean * mean;
            float rstd = rsqrtf(var + 1e-5f);
            int row_g = wrow0 + quad * 4 + r;
            if (row_g < N) {
#pragma unroll
                for (int ct = 0; ct < 8; ct++) {
                    float t = (v[ct][r] - mean) * rstd * gg[ct] + be[ct];
                    t = t > 0.f ? t : 0.f;
                    Out16[(size_t)row_g * D + ct * 16 + ln16] = bf16_rne(t);
                }
            }
        }
    } else {
#pragma unroll
        for (int r = 0; r < 4; r++) {
            int row_g = wrow0 + quad * 4 + r;
            if (row_g < N) {
#pragma unroll
                for (int ct = 0; ct < 8; ct++)
                    Out32[(size_t)row_g * D + ct * 16 + ln16] = v[ct][r];
            }
        }
    }
}

// ---------------------------------------------------------------------------
extern "C" void kernel_launch(void* const* d_in, const int* in_sizes, int n_in,
                              void* d_out, int out_size, void* d_ws, size_t ws_size,
                              hipStream_t stream)
{
    const float* feat = (const float*)d_in[0];
    const float* Ws0  = (const float*)d_in[1];
    const float* Wn0  = (const float*)d_in[2];
    const float* b0   = (const float*)d_in[3];
    const float* Ws1  = (const float*)d_in[4];
    const float* Wn1  = (const float*)d_in[5];
    const float* b1   = (const float*)d_in[6];
    const float* lng  = (const float*)d_in[7];
    const float* lnb  = (const float*)d_in[8];
    const int* esrc   = (const int*)d_in[9];
    const int* edst   = (const int*)d_in[10];
    const int* indeg  = (const int*)d_in[11];

    const int N = NN;
    const int E = in_sizes[9];

    float* out = (float*)d_out;

    // workspace layout (16B-aligned):
    //   feat16 | col | row_ptr | wt0 | wt1 | bsums | boffs | D-region
    //   D-region overlay: [counts + rank] (CSR build) then [h1_16] (compute)
    char* ws = (char*)d_ws;
    size_t o = 0;
    auto alloc = [&](size_t bytes) { char* p = ws + o; o += (bytes + 15) & ~(size_t)15; return p; };
    unsigned short* feat16 = (unsigned short*)alloc((size_t)N * D * 2);
    int* col     = (int*)alloc((size_t)E * 4);
    int* row_ptr = (int*)alloc((size_t)(N + 1) * 4);
    unsigned short* wt0 = (unsigned short*)alloc(128 * 256 * 2);
    unsigned short* wt1 = (unsigned short*)alloc(128 * 256 * 2);
    int* bsums = (int*)alloc(1024);
    int* boffs = (int*)alloc(1024);
    char* regD = alloc((size_t)N * D * 2 > ((size_t)N * 4 + (size_t)E * 4 + 32)
                       ? (size_t)N * D * 2 : ((size_t)N * 4 + (size_t)E * 4 + 32));
    int* counts = (int*)regD;
    int* rank   = (int*)(regD + (((size_t)N * 4 + 15) & ~(size_t)15));
    unsigned short* h116 = (unsigned short*)regD;
    (void)ws_size;

    const int edge_blocks = (E + 255) / 256;
    const int gemm_blocks = (N + 63) / 64;
    const int nb = (N + 1023) / 1024;

    // --- conversions (independent of CSR) ---
    cvt_bf16_kernel<<<(N * D / 4 + 255) / 256, 256, 0, stream>>>(feat, feat16, N * D / 4);
    build_wt_kernel<<<256, 256, 0, stream>>>(Ws0, Wn0, Ws1, Wn1, wt0, wt1);

    // --- CSR build ---
    hipMemsetAsync(counts, 0, (size_t)N * 4, stream);
    hist_rank_kernel<<<edge_blocks, 256, 0, stream>>>(edst, counts, rank, E);
    scan1_kernel<<<nb, 256, 0, stream>>>(counts, row_ptr, bsums, N);
    scan2_kernel<<<1, 256, 0, stream>>>(bsums, boffs, nb);
    scan3_kernel<<<(N + 256) / 256, 256, 0, stream>>>(row_ptr, boffs, N, E);
    fill_stream_kernel<<<edge_blocks, 256, 0, stream>>>(esrc, edst, row_ptr, rank, col, E);

    // --- Layer 0: fused gather + GEMM + LN + ReLU -> h1 (bf16) ---
    fused_layer_kernel<<<gemm_blocks, 256, 0, stream>>>(
        feat16, row_ptr, col, indeg, wt0, b0, lng, lnb, h116, nullptr, N, 1);

    // --- Layer 1: fused gather + GEMM -> out (fp32) ---
    fused_layer_kernel<<<gemm_blocks, 256, 0, stream>>>(
        h116, row_ptr, col, indeg, wt1, b1, nullptr, nullptr, nullptr, out, N, 0);
}

// Round 5
// 499.448 us; speedup vs baseline: 1.0041x; 1.0041x over previous
//
#include <hip/hip_runtime.h>

#define D 128
#define NN 100000

typedef __attribute__((ext_vector_type(8))) short short8;
typedef __attribute__((ext_vector_type(4))) float floatx4;

__device__ inline unsigned short bf16_rne(float f) {
    unsigned int u = __float_as_uint(f);
    u += 0x7fff + ((u >> 16) & 1);
    return (unsigned short)(u >> 16);
}
__device__ inline float bflo(unsigned int u) { return __uint_as_float(u << 16); }
__device__ inline float bfhi(unsigned int u) { return __uint_as_float(u & 0xffff0000u); }

// ---------------------------------------------------------------------------
// CSR build: hist (+rank) -> scan -> streaming fill (no atomics in fill)
// ---------------------------------------------------------------------------
__global__ __launch_bounds__(256) void hist_rank_kernel(
    const int* __restrict__ dst, int* __restrict__ counts,
    int* __restrict__ rank, int E)
{
    int e = blockIdx.x * 256 + threadIdx.x;
    if (e < E) rank[e] = atomicAdd(&counts[dst[e]], 1);
}

__global__ __launch_bounds__(256) void scan1_kernel(
    const int* __restrict__ counts, int* __restrict__ row_ptr,
    int* __restrict__ blockSums, int N)
{
    __shared__ int sd[256];
    int t = threadIdx.x;
    int base = blockIdx.x * 1024;
    int v[4]; int tot = 0;
#pragma unroll
    for (int i = 0; i < 4; i++) {
        int idx = base + t * 4 + i;
        v[i] = (idx < N) ? counts[idx] : 0;
        tot += v[i];
    }
    sd[t] = tot; __syncthreads();
    for (int off = 1; off < 256; off <<= 1) {
        int x = (t >= off) ? sd[t - off] : 0;
        __syncthreads();
        sd[t] += x;
        __syncthreads();
    }
    int excl = sd[t] - tot;
    if (t == 255) blockSums[blockIdx.x] = sd[255];
    int run = excl;
#pragma unroll
    for (int i = 0; i < 4; i++) {
        int idx = base + t * 4 + i;
        if (idx < N) row_ptr[idx] = run;
        run += v[i];
    }
}

__global__ __launch_bounds__(256) void scan2_kernel(
    const int* __restrict__ blockSums, int* __restrict__ blockOffs, int nb)
{
    __shared__ int sd[256];
    int t = threadIdx.x;
    int val = (t < nb) ? blockSums[t] : 0;
    sd[t] = val; __syncthreads();
    for (int off = 1; off < 256; off <<= 1) {
        int x = (t >= off) ? sd[t - off] : 0;
        __syncthreads();
        sd[t] += x;
        __syncthreads();
    }
    if (t < nb) blockOffs[t] = sd[t] - val;
}

__global__ __launch_bounds__(256) void scan3_kernel(
    int* __restrict__ row_ptr, const int* __restrict__ blockOffs, int N, int E)
{
    int i = blockIdx.x * 256 + threadIdx.x;
    if (i < N) row_ptr[i] += blockOffs[i >> 10];
    if (i == N) row_ptr[N] = E;
}

__global__ __launch_bounds__(256) void fill_stream_kernel(
    const int* __restrict__ src, const int* __restrict__ dst,
    const int* __restrict__ row_ptr, const int* __restrict__ rank,
    int* __restrict__ col, int E)
{
    int e = blockIdx.x * 256 + threadIdx.x;
    if (e >= E) return;
    col[row_ptr[dst[e]] + rank[e]] = src[e];
}

// ---------------------------------------------------------------------------
// fp32 -> bf16 conversions
// ---------------------------------------------------------------------------
__global__ __launch_bounds__(256) void cvt_bf16_kernel(
    const float* __restrict__ in, unsigned short* __restrict__ out, int n4)
{
    int i = blockIdx.x * 256 + threadIdx.x;
    if (i >= n4) return;
    float4 v = *(const float4*)(in + (size_t)i * 4);
    unsigned short u[4] = { bf16_rne(v.x), bf16_rne(v.y), bf16_rne(v.z), bf16_rne(v.w) };
    *(uint2*)(out + (size_t)i * 4) = *(uint2*)u;
}

// Wt[layer][n][k] bf16: k<128 -> Ws[k][n], else Wn[k-128][n]
__global__ __launch_bounds__(256) void build_wt_kernel(
    const float* __restrict__ Ws0, const float* __restrict__ Wn0,
    const float* __restrict__ Ws1, const float* __restrict__ Wn1,
    unsigned short* __restrict__ wt0, unsigned short* __restrict__ wt1)
{
    int i = blockIdx.x * 256 + threadIdx.x;   // 0 .. 65535
    int layer = i >> 15;
    int r = i & 32767;
    int n = r >> 8;
    int k = r & 255;
    const float* Ws = layer ? Ws1 : Ws0;
    const float* Wn = layer ? Wn1 : Wn0;
    float v = (k < 128) ? Ws[(size_t)k * 128 + n] : Wn[(size_t)(k - 128) * 128 + n];
    unsigned short* wt = layer ? wt1 : wt0;
    wt[(size_t)n * 256 + k] = bf16_rne(v);
}

// ---------------------------------------------------------------------------
// Gather: msg16[node] = bf16( inv_deg * sum_j h16[col[j]] ).
// 16 lanes x uint4 (8 bf16 = 16B) per row; 4 nodes per wave (one per quad);
// 4-deep neighbor unroll -> 4 outstanding 16B loads per lane. Lean: no LDS,
// low VGPR, 6250 blocks -> high occupancy for latency hiding.
// ---------------------------------------------------------------------------
__global__ __launch_bounds__(256) void gather16_kernel(
    const unsigned short* __restrict__ h16, const int* __restrict__ row_ptr,
    const int* __restrict__ col, const int* __restrict__ in_deg,
    unsigned short* __restrict__ msg16, int N)
{
    const int wave = threadIdx.x >> 6;
    const int lane = threadIdx.x & 63;
    const int quad = lane >> 4;
    const int ln16 = lane & 15;
    const int node = (blockIdx.x * 4 + wave) * 4 + quad;
    if (node >= N) return;

    const size_t lo = (size_t)ln16 * 8;
    int beg = row_ptr[node];
    int end = row_ptr[node + 1];

    float f[8] = {0.f,0.f,0.f,0.f,0.f,0.f,0.f,0.f};
    int j = beg;
    for (; j + 4 <= end; j += 4) {
        int c0 = col[j], c1 = col[j + 1], c2 = col[j + 2], c3 = col[j + 3];
        uint4 u0 = *(const uint4*)(h16 + (size_t)c0 * D + lo);
        uint4 u1 = *(const uint4*)(h16 + (size_t)c1 * D + lo);
        uint4 u2 = *(const uint4*)(h16 + (size_t)c2 * D + lo);
        uint4 u3 = *(const uint4*)(h16 + (size_t)c3 * D + lo);
        f[0] += bflo(u0.x) + bflo(u1.x) + bflo(u2.x) + bflo(u3.x);
        f[1] += bfhi(u0.x) + bfhi(u1.x) + bfhi(u2.x) + bfhi(u3.x);
        f[2] += bflo(u0.y) + bflo(u1.y) + bflo(u2.y) + bflo(u3.y);
        f[3] += bfhi(u0.y) + bfhi(u1.y) + bfhi(u2.y) + bfhi(u3.y);
        f[4] += bflo(u0.z) + bflo(u1.z) + bflo(u2.z) + bflo(u3.z);
        f[5] += bfhi(u0.z) + bfhi(u1.z) + bfhi(u2.z) + bfhi(u3.z);
        f[6] += bflo(u0.w) + bflo(u1.w) + bflo(u2.w) + bflo(u3.w);
        f[7] += bfhi(u0.w) + bfhi(u1.w) + bfhi(u2.w) + bfhi(u3.w);
    }
    for (; j < end; ++j) {
        uint4 u0 = *(const uint4*)(h16 + (size_t)col[j] * D + lo);
        f[0] += bflo(u0.x); f[1] += bfhi(u0.x);
        f[2] += bflo(u0.y); f[3] += bfhi(u0.y);
        f[4] += bflo(u0.z); f[5] += bfhi(u0.z);
        f[6] += bflo(u0.w); f[7] += bfhi(u0.w);
    }
    int dg = in_deg[node];
    float invd = 1.f / (float)(dg > 1 ? dg : 1);
    unsigned short us[8];
#pragma unroll
    for (int i = 0; i < 8; i++) us[i] = bf16_rne(f[i] * invd);
    *(uint4*)(msg16 + (size_t)node * D + lo) = *(const uint4*)us;
}

// ---------------------------------------------------------------------------
// MFMA dual-GEMM, LDS-free & barrier-free. Wave w of block b owns rows
// wrow0..+15. A-fragments: 4 from A16 (self), 4 from Msg16 (pre-scaled mean),
// both row-major bf16 short8 loads. B from global Wt (64KB, L2-resident).
// 64 MFMAs (16x16x32) per wave. Fused bias (+LN+ReLU) epilogue.
// ---------------------------------------------------------------------------
__global__ __launch_bounds__(256) void mfma16_kernel(
    const unsigned short* __restrict__ A16, const unsigned short* __restrict__ Msg16,
    const unsigned short* __restrict__ Wt,   // [128 n][256 k] bf16
    const float* __restrict__ bias,
    const float* __restrict__ ln_g, const float* __restrict__ ln_b,
    unsigned short* __restrict__ Out16, float* __restrict__ Out32,
    int N, int do_ln)
{
    const int wave = threadIdx.x >> 6;
    const int lane = threadIdx.x & 63;
    const int quad = lane >> 4;
    const int ln16 = lane & 15;
    const int wrow0 = blockIdx.x * 64 + wave * 16;

    short8 afr[8];
    const int arow = wrow0 + ln16;
    const bool arv = arow < N;
#pragma unroll
    for (int kc = 0; kc < 4; kc++) {
        if (arv) {
            afr[kc]     = *(const short8*)(A16  + (size_t)arow * D + kc * 32 + quad * 8);
            afr[4 + kc] = *(const short8*)(Msg16 + (size_t)arow * D + kc * 32 + quad * 8);
        } else {
            afr[kc] = (short8){0,0,0,0,0,0,0,0};
            afr[4 + kc] = (short8){0,0,0,0,0,0,0,0};
        }
    }

    floatx4 acc[8];
#pragma unroll
    for (int ct = 0; ct < 8; ct++) acc[ct] = (floatx4){0.f, 0.f, 0.f, 0.f};

#pragma unroll
    for (int kc = 0; kc < 8; kc++) {
#pragma unroll
        for (int ct = 0; ct < 8; ct++) {
            short8 b = *(const short8*)(Wt + ((size_t)(ct * 16 + ln16)) * 256 + kc * 32 + quad * 8);
            acc[ct] = __builtin_amdgcn_mfma_f32_16x16x32_bf16(afr[kc], b, acc[ct], 0, 0, 0);
        }
    }

    // ---- Epilogue: bias (+ LN + ReLU) ----
    float bb[8];
#pragma unroll
    for (int ct = 0; ct < 8; ct++) bb[ct] = bias[ct * 16 + ln16];

    float v[8][4];
#pragma unroll
    for (int ct = 0; ct < 8; ct++)
#pragma unroll
        for (int r = 0; r < 4; r++) v[ct][r] = acc[ct][r] + bb[ct];

    if (do_ln) {
        float gg[8], be[8];
#pragma unroll
        for (int ct = 0; ct < 8; ct++) {
            gg[ct] = ln_g[ct * 16 + ln16];
            be[ct] = ln_b[ct * 16 + ln16];
        }
        float s[4] = {0.f,0.f,0.f,0.f}, s2[4] = {0.f,0.f,0.f,0.f};
#pragma unroll
        for (int ct = 0; ct < 8; ct++)
#pragma unroll
            for (int r = 0; r < 4; r++) { s[r] += v[ct][r]; s2[r] += v[ct][r] * v[ct][r]; }
#pragma unroll
        for (int off = 1; off < 16; off <<= 1) {
#pragma unroll
            for (int r = 0; r < 4; r++) {
                s[r]  += __shfl_xor(s[r],  off);
                s2[r] += __shfl_xor(s2[r], off);
            }
        }
#pragma unroll
        for (int r = 0; r < 4; r++) {
            float mean = s[r] * (1.f / 128.f);
            float var  = s2[r] * (1.f / 128.f) - mean * mean;
            float rstd = rsqrtf(var + 1e-5f);
            int row_g = wrow0 + quad * 4 + r;
            if (row_g < N) {
#pragma unroll
                for (int ct = 0; ct < 8; ct++) {
                    float t = (v[ct][r] - mean) * rstd * gg[ct] + be[ct];
                    t = t > 0.f ? t : 0.f;
                    Out16[(size_t)row_g * D + ct * 16 + ln16] = bf16_rne(t);
                }
            }
        }
    } else {
#pragma unroll
        for (int r = 0; r < 4; r++) {
            int row_g = wrow0 + quad * 4 + r;
            if (row_g < N) {
#pragma unroll
                for (int ct = 0; ct < 8; ct++)
                    Out32[(size_t)row_g * D + ct * 16 + ln16] = v[ct][r];
            }
        }
    }
}

// ---------------------------------------------------------------------------
extern "C" void kernel_launch(void* const* d_in, const int* in_sizes, int n_in,
                              void* d_out, int out_size, void* d_ws, size_t ws_size,
                              hipStream_t stream)
{
    const float* feat = (const float*)d_in[0];
    const float* Ws0  = (const float*)d_in[1];
    const float* Wn0  = (const float*)d_in[2];
    const float* b0   = (const float*)d_in[3];
    const float* Ws1  = (const float*)d_in[4];
    const float* Wn1  = (const float*)d_in[5];
    const float* b1   = (const float*)d_in[6];
    const float* lng  = (const float*)d_in[7];
    const float* lnb  = (const float*)d_in[8];
    const int* esrc   = (const int*)d_in[9];
    const int* edst   = (const int*)d_in[10];
    const int* indeg  = (const int*)d_in[11];

    const int N = NN;
    const int E = in_sizes[9];

    float* out = (float*)d_out;

    // workspace layout (16B-aligned):
    //   feat16 | col | row_ptr | wt0 | wt1 | bsums | boffs | D-region
    //   D-region overlay: [counts + rank] (CSR build) then [h1_16] (compute)
    // msg16 ping-pong: layer0 -> d_out (bf16, scratch until final write),
    //                  layer1 -> feat16 buffer (dead after layer 0).
    char* ws = (char*)d_ws;
    size_t o = 0;
    auto alloc = [&](size_t bytes) { char* p = ws + o; o += (bytes + 15) & ~(size_t)15; return p; };
    unsigned short* feat16 = (unsigned short*)alloc((size_t)N * D * 2);
    int* col     = (int*)alloc((size_t)E * 4);
    int* row_ptr = (int*)alloc((size_t)(N + 1) * 4);
    unsigned short* wt0 = (unsigned short*)alloc(128 * 256 * 2);
    unsigned short* wt1 = (unsigned short*)alloc(128 * 256 * 2);
    int* bsums = (int*)alloc(1024);
    int* boffs = (int*)alloc(1024);
    char* regD = alloc((size_t)N * D * 2 > ((size_t)N * 4 + (size_t)E * 4 + 32)
                       ? (size_t)N * D * 2 : ((size_t)N * 4 + (size_t)E * 4 + 32));
    int* counts = (int*)regD;
    int* rank   = (int*)(regD + (((size_t)N * 4 + 15) & ~(size_t)15));
    unsigned short* h116 = (unsigned short*)regD;
    unsigned short* msg0 = (unsigned short*)d_out;   // 25.6MB of the 51.2MB out buf
    unsigned short* msg1 = feat16;
    (void)ws_size;

    const int edge_blocks = (E + 255) / 256;
    const int gemm_blocks = (N + 63) / 64;
    const int gather_blocks = (N + 15) / 16;
    const int nb = (N + 1023) / 1024;

    // --- conversions (independent of CSR) ---
    cvt_bf16_kernel<<<(N * D / 4 + 255) / 256, 256, 0, stream>>>(feat, feat16, N * D / 4);
    build_wt_kernel<<<256, 256, 0, stream>>>(Ws0, Wn0, Ws1, Wn1, wt0, wt1);

    // --- CSR build ---
    hipMemsetAsync(counts, 0, (size_t)N * 4, stream);
    hist_rank_kernel<<<edge_blocks, 256, 0, stream>>>(edst, counts, rank, E);
    scan1_kernel<<<nb, 256, 0, stream>>>(counts, row_ptr, bsums, N);
    scan2_kernel<<<1, 256, 0, stream>>>(bsums, boffs, nb);
    scan3_kernel<<<(N + 256) / 256, 256, 0, stream>>>(row_ptr, boffs, N, E);
    fill_stream_kernel<<<edge_blocks, 256, 0, stream>>>(esrc, edst, row_ptr, rank, col, E);

    // --- Layer 0 ---
    gather16_kernel<<<gather_blocks, 256, 0, stream>>>(feat16, row_ptr, col, indeg, msg0, N);
    mfma16_kernel<<<gemm_blocks, 256, 0, stream>>>(
        feat16, msg0, wt0, b0, lng, lnb, h116, nullptr, N, 1);

    // --- Layer 1 ---
    gather16_kernel<<<gather_blocks, 256, 0, stream>>>(h116, row_ptr, col, indeg, msg1, N);
    mfma16_kernel<<<gemm_blocks, 256, 0, stream>>>(
        h116, msg1, wt1, b1, nullptr, nullptr, nullptr, out, N, 0);
}

// Round 6
// 467.928 us; speedup vs baseline: 1.0718x; 1.0674x over previous
//
#include <hip/hip_runtime.h>

#define D 128
#define NN 100000

typedef __attribute__((ext_vector_type(8))) short short8;
typedef __attribute__((ext_vector_type(16))) float floatx16;

__device__ inline unsigned short bf16_rne(float f) {
    unsigned int u = __float_as_uint(f);
    u += 0x7fff + ((u >> 16) & 1);
    return (unsigned short)(u >> 16);
}
__device__ inline float bflo(unsigned int u) { return __uint_as_float(u << 16); }
__device__ inline float bfhi(unsigned int u) { return __uint_as_float(u & 0xffff0000u); }

// ---------------------------------------------------------------------------
// Fused prep: [0,12500) cvt feat->bf16 | [12500,12756) build Wt | rest zero counts
// ---------------------------------------------------------------------------
__global__ __launch_bounds__(256) void prep_kernel(
    const float* __restrict__ feat, unsigned short* __restrict__ feat16,
    const float* __restrict__ Ws0, const float* __restrict__ Wn0,
    const float* __restrict__ Ws1, const float* __restrict__ Wn1,
    unsigned short* __restrict__ wt0, unsigned short* __restrict__ wt1,
    int* __restrict__ counts)
{
    int bid = blockIdx.x;
    if (bid < 12500) {
        int i = bid * 256 + threadIdx.x;                 // float4 index
        float4 v = *(const float4*)(feat + (size_t)i * 4);
        unsigned short u[4] = { bf16_rne(v.x), bf16_rne(v.y), bf16_rne(v.z), bf16_rne(v.w) };
        *(uint2*)(feat16 + (size_t)i * 4) = *(uint2*)u;
    } else if (bid < 12756) {
        int i = (bid - 12500) * 256 + threadIdx.x;       // 0..65535
        int layer = i >> 15;
        int r = i & 32767;
        int n = r >> 8;
        int k = r & 255;
        const float* Ws = layer ? Ws1 : Ws0;
        const float* Wn = layer ? Wn1 : Wn0;
        float v = (k < 128) ? Ws[(size_t)k * 128 + n] : Wn[(size_t)(k - 128) * 128 + n];
        unsigned short* wt = layer ? wt1 : wt0;
        wt[(size_t)n * 256 + k] = bf16_rne(v);
    } else {
        int i = (bid - 12756) * 256 + threadIdx.x;       // uint4 index
        if (i < NN / 4) ((uint4*)counts)[i] = make_uint4(0u, 0u, 0u, 0u);
    }
}

// ---------------------------------------------------------------------------
// CSR build: hist (+rank) -> scan -> streaming fill (no atomics in fill)
// ---------------------------------------------------------------------------
__global__ __launch_bounds__(256) void hist_rank_kernel(
    const int* __restrict__ dst, int* __restrict__ counts,
    int* __restrict__ rank, int E)
{
    int e = blockIdx.x * 256 + threadIdx.x;
    if (e < E) rank[e] = atomicAdd(&counts[dst[e]], 1);
}

__global__ __launch_bounds__(256) void scan1_kernel(
    const int* __restrict__ counts, int* __restrict__ row_ptr,
    int* __restrict__ blockSums, int N)
{
    __shared__ int sd[256];
    int t = threadIdx.x;
    int base = blockIdx.x * 1024;
    int v[4]; int tot = 0;
#pragma unroll
    for (int i = 0; i < 4; i++) {
        int idx = base + t * 4 + i;
        v[i] = (idx < N) ? counts[idx] : 0;
        tot += v[i];
    }
    sd[t] = tot; __syncthreads();
    for (int off = 1; off < 256; off <<= 1) {
        int x = (t >= off) ? sd[t - off] : 0;
        __syncthreads();
        sd[t] += x;
        __syncthreads();
    }
    int excl = sd[t] - tot;
    if (t == 255) blockSums[blockIdx.x] = sd[255];
    int run = excl;
#pragma unroll
    for (int i = 0; i < 4; i++) {
        int idx = base + t * 4 + i;
        if (idx < N) row_ptr[idx] = run;
        run += v[i];
    }
}

__global__ __launch_bounds__(256) void scan2_kernel(
    const int* __restrict__ blockSums, int* __restrict__ blockOffs, int nb)
{
    __shared__ int sd[256];
    int t = threadIdx.x;
    int val = (t < nb) ? blockSums[t] : 0;
    sd[t] = val; __syncthreads();
    for (int off = 1; off < 256; off <<= 1) {
        int x = (t >= off) ? sd[t - off] : 0;
        __syncthreads();
        sd[t] += x;
        __syncthreads();
    }
    if (t < nb) blockOffs[t] = sd[t] - val;
}

__global__ __launch_bounds__(256) void scan3_kernel(
    int* __restrict__ row_ptr, const int* __restrict__ blockOffs, int N, int E)
{
    int i = blockIdx.x * 256 + threadIdx.x;
    if (i < N) row_ptr[i] += blockOffs[i >> 10];
    if (i == N) row_ptr[N] = E;
}

__global__ __launch_bounds__(256) void fill_stream_kernel(
    const int* __restrict__ src, const int* __restrict__ dst,
    const int* __restrict__ row_ptr, const int* __restrict__ rank,
    int* __restrict__ col, int E)
{
    int e = blockIdx.x * 256 + threadIdx.x;
    if (e >= E) return;
    col[row_ptr[dst[e]] + rank[e]] = src[e];
}

// ---------------------------------------------------------------------------
// Gather: msg16[node] = bf16( inv_deg * sum_j h16[col[j]] ).
// 16 lanes x uint4 (8 bf16 = 16B) per row; 4 nodes per wave; 4-deep unroll.
// ---------------------------------------------------------------------------
__global__ __launch_bounds__(256) void gather16_kernel(
    const unsigned short* __restrict__ h16, const int* __restrict__ row_ptr,
    const int* __restrict__ col, const int* __restrict__ in_deg,
    unsigned short* __restrict__ msg16, int N)
{
    const int wave = threadIdx.x >> 6;
    const int lane = threadIdx.x & 63;
    const int quad = lane >> 4;
    const int ln16 = lane & 15;
    const int node = (blockIdx.x * 4 + wave) * 4 + quad;
    if (node >= N) return;

    const size_t lo = (size_t)ln16 * 8;
    int beg = row_ptr[node];
    int end = row_ptr[node + 1];

    float f[8] = {0.f,0.f,0.f,0.f,0.f,0.f,0.f,0.f};
    int j = beg;
    for (; j + 4 <= end; j += 4) {
        int c0 = col[j], c1 = col[j + 1], c2 = col[j + 2], c3 = col[j + 3];
        uint4 u0 = *(const uint4*)(h16 + (size_t)c0 * D + lo);
        uint4 u1 = *(const uint4*)(h16 + (size_t)c1 * D + lo);
        uint4 u2 = *(const uint4*)(h16 + (size_t)c2 * D + lo);
        uint4 u3 = *(const uint4*)(h16 + (size_t)c3 * D + lo);
        f[0] += bflo(u0.x) + bflo(u1.x) + bflo(u2.x) + bflo(u3.x);
        f[1] += bfhi(u0.x) + bfhi(u1.x) + bfhi(u2.x) + bfhi(u3.x);
        f[2] += bflo(u0.y) + bflo(u1.y) + bflo(u2.y) + bflo(u3.y);
        f[3] += bfhi(u0.y) + bfhi(u1.y) + bfhi(u2.y) + bfhi(u3.y);
        f[4] += bflo(u0.z) + bflo(u1.z) + bflo(u2.z) + bflo(u3.z);
        f[5] += bfhi(u0.z) + bfhi(u1.z) + bfhi(u2.z) + bfhi(u3.z);
        f[6] += bflo(u0.w) + bflo(u1.w) + bflo(u2.w) + bflo(u3.w);
        f[7] += bfhi(u0.w) + bfhi(u1.w) + bfhi(u2.w) + bfhi(u3.w);
    }
    for (; j < end; ++j) {
        uint4 u0 = *(const uint4*)(h16 + (size_t)col[j] * D + lo);
        f[0] += bflo(u0.x); f[1] += bfhi(u0.x);
        f[2] += bflo(u0.y); f[3] += bfhi(u0.y);
        f[4] += bflo(u0.z); f[5] += bfhi(u0.z);
        f[6] += bflo(u0.w); f[7] += bfhi(u0.w);
    }
    int dg = in_deg[node];
    float invd = 1.f / (float)(dg > 1 ? dg : 1);
    unsigned short us[8];
#pragma unroll
    for (int i = 0; i < 8; i++) us[i] = bf16_rne(f[i] * invd);
    *(uint4*)(msg16 + (size_t)node * D + lo) = *(const uint4*)us;
}

// ---------------------------------------------------------------------------
// MFMA dual-GEMM with 32x32x16_bf16, LDS-free & barrier-free.
// Block = 256 thr = 4 waves; block owns 128 rows, wave w rows wrow0..+31.
// A: m=lane&31, k=(lane>>5)*8+j  -> short8 from row-major A16/Msg16.
// B: n=lane&31, k=(lane>>5)*8+j  -> short8 from n-major Wt.
// C/D: col=lane&31, row=(reg&3)+8*(reg>>2)+4*(lane>>5).
// K=256 (first 128 self, last 128 msg); N=128 -> 4 ct tiles; 64 MFMAs/wave.
// ---------------------------------------------------------------------------
__global__ __launch_bounds__(256) void mfma32_kernel(
    const unsigned short* __restrict__ A16, const unsigned short* __restrict__ Msg16,
    const unsigned short* __restrict__ Wt,   // [128 n][256 k] bf16
    const float* __restrict__ bias,
    const float* __restrict__ ln_g, const float* __restrict__ ln_b,
    unsigned short* __restrict__ Out16, float* __restrict__ Out32,
    int N, int do_ln)
{
    const int wave = threadIdx.x >> 6;
    const int lane = threadIdx.x & 63;
    const int half = lane >> 5;
    const int n32  = lane & 31;
    const int wrow0 = blockIdx.x * 128 + wave * 32;

    const int arow = wrow0 + n32;            // A row this lane feeds (m=lane&31)
    const bool arv = arow < N;
    const size_t koff = (size_t)half * 8;

    floatx16 acc[4];
#pragma unroll
    for (int ct = 0; ct < 4; ct++)
#pragma unroll
        for (int r = 0; r < 16; r++) acc[ct][r] = 0.f;

#pragma unroll
    for (int hs = 0; hs < 2; hs++) {
        const unsigned short* Asrc = hs ? Msg16 : A16;
#pragma unroll
        for (int kc = 0; kc < 8; kc++) {
            short8 a;
            if (arv) a = *(const short8*)(Asrc + (size_t)arow * D + kc * 16 + koff);
            else     a = (short8){0,0,0,0,0,0,0,0};
            const size_t kglob = (size_t)hs * 128 + kc * 16 + koff;
#pragma unroll
            for (int ct = 0; ct < 4; ct++) {
                short8 b = *(const short8*)(Wt + (size_t)(ct * 32 + n32) * 256 + kglob);
                acc[ct] = __builtin_amdgcn_mfma_f32_32x32x16_bf16(a, b, acc[ct], 0, 0, 0);
            }
        }
    }

    // ---- Epilogue ----
    float bb[4];
#pragma unroll
    for (int ct = 0; ct < 4; ct++) bb[ct] = bias[ct * 32 + n32];

    float v[4][16];
#pragma unroll
    for (int ct = 0; ct < 4; ct++)
#pragma unroll
        for (int r = 0; r < 16; r++) v[ct][r] = acc[ct][r] + bb[ct];

    if (do_ln) {
        float gg[4], be[4];
#pragma unroll
        for (int ct = 0; ct < 4; ct++) {
            gg[ct] = ln_g[ct * 32 + n32];
            be[ct] = ln_b[ct * 32 + n32];
        }
        float s[16], s2[16];
#pragma unroll
        for (int r = 0; r < 16; r++) {
            s[r]  = v[0][r] + v[1][r] + v[2][r] + v[3][r];
            s2[r] = v[0][r]*v[0][r] + v[1][r]*v[1][r] + v[2][r]*v[2][r] + v[3][r]*v[3][r];
        }
#pragma unroll
        for (int off = 1; off < 32; off <<= 1) {
#pragma unroll
            for (int r = 0; r < 16; r++) {
                s[r]  += __shfl_xor(s[r],  off);
                s2[r] += __shfl_xor(s2[r], off);
            }
        }
#pragma unroll
        for (int r = 0; r < 16; r++) {
            float mean = s[r] * (1.f / 128.f);
            float var  = s2[r] * (1.f / 128.f) - mean * mean;
            float rstd = rsqrtf(var + 1e-5f);
            int row_g = wrow0 + (r & 3) + 8 * (r >> 2) + 4 * half;
            if (row_g < N) {
#pragma unroll
                for (int ct = 0; ct < 4; ct++) {
                    float t = (v[ct][r] - mean) * rstd * gg[ct] + be[ct];
                    t = t > 0.f ? t : 0.f;
                    Out16[(size_t)row_g * D + ct * 32 + n32] = bf16_rne(t);
                }
            }
        }
    } else {
#pragma unroll
        for (int r = 0; r < 16; r++) {
            int row_g = wrow0 + (r & 3) + 8 * (r >> 2) + 4 * half;
            if (row_g < N) {
#pragma unroll
                for (int ct = 0; ct < 4; ct++)
                    Out32[(size_t)row_g * D + ct * 32 + n32] = v[ct][r];
            }
        }
    }
}

// ---------------------------------------------------------------------------
extern "C" void kernel_launch(void* const* d_in, const int* in_sizes, int n_in,
                              void* d_out, int out_size, void* d_ws, size_t ws_size,
                              hipStream_t stream)
{
    const float* feat = (const float*)d_in[0];
    const float* Ws0  = (const float*)d_in[1];
    const float* Wn0  = (const float*)d_in[2];
    const float* b0   = (const float*)d_in[3];
    const float* Ws1  = (const float*)d_in[4];
    const float* Wn1  = (const float*)d_in[5];
    const float* b1   = (const float*)d_in[6];
    const float* lng  = (const float*)d_in[7];
    const float* lnb  = (const float*)d_in[8];
    const int* esrc   = (const int*)d_in[9];
    const int* edst   = (const int*)d_in[10];
    const int* indeg  = (const int*)d_in[11];

    const int N = NN;
    const int E = in_sizes[9];

    float* out = (float*)d_out;

    // workspace: feat16 | col | row_ptr | wt0 | wt1 | bsums | boffs | D-region
    // D-region overlay: [counts + rank] (CSR build) then [h1_16] (compute)
    // msg ping-pong: layer0 msg -> d_out (bf16 scratch); layer1 msg -> feat16.
    char* ws = (char*)d_ws;
    size_t o = 0;
    auto alloc = [&](size_t bytes) { char* p = ws + o; o += (bytes + 15) & ~(size_t)15; return p; };
    unsigned short* feat16 = (unsigned short*)alloc((size_t)N * D * 2);
    int* col     = (int*)alloc((size_t)E * 4);
    int* row_ptr = (int*)alloc((size_t)(N + 1) * 4);
    unsigned short* wt0 = (unsigned short*)alloc(128 * 256 * 2);
    unsigned short* wt1 = (unsigned short*)alloc(128 * 256 * 2);
    int* bsums = (int*)alloc(1024);
    int* boffs = (int*)alloc(1024);
    char* regD = alloc((size_t)N * D * 2 > ((size_t)N * 4 + (size_t)E * 4 + 32)
                       ? (size_t)N * D * 2 : ((size_t)N * 4 + (size_t)E * 4 + 32));
    int* counts = (int*)regD;
    int* rank   = (int*)(regD + (((size_t)N * 4 + 15) & ~(size_t)15));
    unsigned short* h116 = (unsigned short*)regD;
    unsigned short* msg0 = (unsigned short*)d_out;
    unsigned short* msg1 = feat16;
    (void)ws_size;

    const int edge_blocks = (E + 255) / 256;
    const int gemm_blocks = (N + 127) / 128;
    const int gather_blocks = (N + 15) / 16;
    const int nb = (N + 1023) / 1024;
    const int zero_blocks = (N / 4 + 255) / 256;

    // --- fused prep: cvt feat->bf16, build Wt, zero counts ---
    prep_kernel<<<12500 + 256 + zero_blocks, 256, 0, stream>>>(
        feat, feat16, Ws0, Wn0, Ws1, Wn1, wt0, wt1, counts);

    // --- CSR build ---
    hist_rank_kernel<<<edge_blocks, 256, 0, stream>>>(edst, counts, rank, E);
    scan1_kernel<<<nb, 256, 0, stream>>>(counts, row_ptr, bsums, N);
    scan2_kernel<<<1, 256, 0, stream>>>(bsums, boffs, nb);
    scan3_kernel<<<(N + 256) / 256, 256, 0, stream>>>(row_ptr, boffs, N, E);
    fill_stream_kernel<<<edge_blocks, 256, 0, stream>>>(esrc, edst, row_ptr, rank, col, E);

    // --- Layer 0 ---
    gather16_kernel<<<gather_blocks, 256, 0, stream>>>(feat16, row_ptr, col, indeg, msg0, N);
    mfma32_kernel<<<gemm_blocks, 256, 0, stream>>>(
        feat16, msg0, wt0, b0, lng, lnb, h116, nullptr, N, 1);

    // --- Layer 1 ---
    gather16_kernel<<<gather_blocks, 256, 0, stream>>>(h116, row_ptr, col, indeg, msg1, N);
    mfma32_kernel<<<gemm_blocks, 256, 0, stream>>>(
        h116, msg1, wt1, b1, nullptr, nullptr, nullptr, out, N, 0);
}

// Round 7
// 428.756 us; speedup vs baseline: 1.1697x; 1.0914x over previous
//
#include <hip/hip_runtime.h>

#define D 128
#define NN 100000

typedef __attribute__((ext_vector_type(8))) short short8;
typedef __attribute__((ext_vector_type(16))) float floatx16;

__device__ inline unsigned short bf16_rne(float f) {
    unsigned int u = __float_as_uint(f);
    u += 0x7fff + ((u >> 16) & 1);
    return (unsigned short)(u >> 16);
}
__device__ inline float bflo(unsigned int u) { return __uint_as_float(u << 16); }
__device__ inline float bfhi(unsigned int u) { return __uint_as_float(u & 0xffff0000u); }

// ---------------------------------------------------------------------------
// Fused prep: [0,12500) cvt feat->bf16 | [12500,12756) build Wt | rest zero counts
// ---------------------------------------------------------------------------
__global__ __launch_bounds__(256) void prep_kernel(
    const float* __restrict__ feat, unsigned short* __restrict__ feat16,
    const float* __restrict__ Ws0, const float* __restrict__ Wn0,
    const float* __restrict__ Ws1, const float* __restrict__ Wn1,
    unsigned short* __restrict__ wt0, unsigned short* __restrict__ wt1,
    int* __restrict__ counts)
{
    int bid = blockIdx.x;
    if (bid < 12500) {
        int i = bid * 256 + threadIdx.x;                 // float4 index
        float4 v = *(const float4*)(feat + (size_t)i * 4);
        unsigned short u[4] = { bf16_rne(v.x), bf16_rne(v.y), bf16_rne(v.z), bf16_rne(v.w) };
        *(uint2*)(feat16 + (size_t)i * 4) = *(uint2*)u;
    } else if (bid < 12756) {
        int i = (bid - 12500) * 256 + threadIdx.x;       // 0..65535
        int layer = i >> 15;
        int r = i & 32767;
        int n = r >> 8;
        int k = r & 255;
        const float* Ws = layer ? Ws1 : Ws0;
        const float* Wn = layer ? Wn1 : Wn0;
        float v = (k < 128) ? Ws[(size_t)k * 128 + n] : Wn[(size_t)(k - 128) * 128 + n];
        unsigned short* wt = layer ? wt1 : wt0;
        wt[(size_t)n * 256 + k] = bf16_rne(v);
    } else {
        int i = (bid - 12756) * 256 + threadIdx.x;       // uint4 index
        if (i < NN / 4) ((uint4*)counts)[i] = make_uint4(0u, 0u, 0u, 0u);
    }
}

// ---------------------------------------------------------------------------
// CSR build: hist (+rank) -> scan -> streaming fill (no atomics in fill)
// ---------------------------------------------------------------------------
__global__ __launch_bounds__(256) void hist_rank_kernel(
    const int* __restrict__ dst, int* __restrict__ counts,
    int* __restrict__ rank, int E)
{
    int e = blockIdx.x * 256 + threadIdx.x;
    if (e < E) rank[e] = atomicAdd(&counts[dst[e]], 1);
}

__global__ __launch_bounds__(256) void scan1_kernel(
    const int* __restrict__ counts, int* __restrict__ row_ptr,
    int* __restrict__ blockSums, int N)
{
    __shared__ int sd[256];
    int t = threadIdx.x;
    int base = blockIdx.x * 1024;
    int v[4]; int tot = 0;
#pragma unroll
    for (int i = 0; i < 4; i++) {
        int idx = base + t * 4 + i;
        v[i] = (idx < N) ? counts[idx] : 0;
        tot += v[i];
    }
    sd[t] = tot; __syncthreads();
    for (int off = 1; off < 256; off <<= 1) {
        int x = (t >= off) ? sd[t - off] : 0;
        __syncthreads();
        sd[t] += x;
        __syncthreads();
    }
    int excl = sd[t] - tot;
    if (t == 255) blockSums[blockIdx.x] = sd[255];
    int run = excl;
#pragma unroll
    for (int i = 0; i < 4; i++) {
        int idx = base + t * 4 + i;
        if (idx < N) row_ptr[idx] = run;
        run += v[i];
    }
}

__global__ __launch_bounds__(256) void scan2_kernel(
    const int* __restrict__ blockSums, int* __restrict__ blockOffs, int nb)
{
    __shared__ int sd[256];
    int t = threadIdx.x;
    int val = (t < nb) ? blockSums[t] : 0;
    sd[t] = val; __syncthreads();
    for (int off = 1; off < 256; off <<= 1) {
        int x = (t >= off) ? sd[t - off] : 0;
        __syncthreads();
        sd[t] += x;
        __syncthreads();
    }
    if (t < nb) blockOffs[t] = sd[t] - val;
}

__global__ __launch_bounds__(256) void scan3_kernel(
    int* __restrict__ row_ptr, const int* __restrict__ blockOffs, int N, int E)
{
    int i = blockIdx.x * 256 + threadIdx.x;
    if (i < N) row_ptr[i] += blockOffs[i >> 10];
    if (i == N) row_ptr[N] = E;
}

__global__ __launch_bounds__(256) void fill_stream_kernel(
    const int* __restrict__ src, const int* __restrict__ dst,
    const int* __restrict__ row_ptr, const int* __restrict__ rank,
    int* __restrict__ col, int E)
{
    int e = blockIdx.x * 256 + threadIdx.x;
    if (e >= E) return;
    col[row_ptr[dst[e]] + rank[e]] = src[e];
}

// ---------------------------------------------------------------------------
// Gather: msg16[node] = bf16( inv_deg * sum_j h16[col[j]] ).
// 16 lanes x uint4 (8 bf16 = 16B) per row; 4 nodes per wave; 4-deep unroll.
// Known-good at ~79us / 260MB FETCH (L2-miss-path floor).
// ---------------------------------------------------------------------------
__global__ __launch_bounds__(256) void gather16_kernel(
    const unsigned short* __restrict__ h16, const int* __restrict__ row_ptr,
    const int* __restrict__ col, const int* __restrict__ in_deg,
    unsigned short* __restrict__ msg16, int N)
{
    const int wave = threadIdx.x >> 6;
    const int lane = threadIdx.x & 63;
    const int quad = lane >> 4;
    const int ln16 = lane & 15;
    const int node = (blockIdx.x * 4 + wave) * 4 + quad;
    if (node >= N) return;

    const size_t lo = (size_t)ln16 * 8;
    int beg = row_ptr[node];
    int end = row_ptr[node + 1];

    float f[8] = {0.f,0.f,0.f,0.f,0.f,0.f,0.f,0.f};
    int j = beg;
    for (; j + 4 <= end; j += 4) {
        int c0 = col[j], c1 = col[j + 1], c2 = col[j + 2], c3 = col[j + 3];
        uint4 u0 = *(const uint4*)(h16 + (size_t)c0 * D + lo);
        uint4 u1 = *(const uint4*)(h16 + (size_t)c1 * D + lo);
        uint4 u2 = *(const uint4*)(h16 + (size_t)c2 * D + lo);
        uint4 u3 = *(const uint4*)(h16 + (size_t)c3 * D + lo);
        f[0] += bflo(u0.x) + bflo(u1.x) + bflo(u2.x) + bflo(u3.x);
        f[1] += bfhi(u0.x) + bfhi(u1.x) + bfhi(u2.x) + bfhi(u3.x);
        f[2] += bflo(u0.y) + bflo(u1.y) + bflo(u2.y) + bflo(u3.y);
        f[3] += bfhi(u0.y) + bfhi(u1.y) + bfhi(u2.y) + bfhi(u3.y);
        f[4] += bflo(u0.z) + bflo(u1.z) + bflo(u2.z) + bflo(u3.z);
        f[5] += bfhi(u0.z) + bfhi(u1.z) + bfhi(u2.z) + bfhi(u3.z);
        f[6] += bflo(u0.w) + bflo(u1.w) + bflo(u2.w) + bflo(u3.w);
        f[7] += bfhi(u0.w) + bfhi(u1.w) + bfhi(u2.w) + bfhi(u3.w);
    }
    for (; j < end; ++j) {
        uint4 u0 = *(const uint4*)(h16 + (size_t)col[j] * D + lo);
        f[0] += bflo(u0.x); f[1] += bfhi(u0.x);
        f[2] += bflo(u0.y); f[3] += bfhi(u0.y);
        f[4] += bflo(u0.z); f[5] += bfhi(u0.z);
        f[6] += bflo(u0.w); f[7] += bfhi(u0.w);
    }
    int dg = in_deg[node];
    float invd = 1.f / (float)(dg > 1 ? dg : 1);
    unsigned short us[8];
#pragma unroll
    for (int i = 0; i < 8; i++) us[i] = bf16_rne(f[i] * invd);
    *(uint4*)(msg16 + (size_t)node * D + lo) = *(const uint4*)us;
}

// ---------------------------------------------------------------------------
// MFMA dual-GEMM 32x32x16_bf16, B staged in LDS (64KB, one barrier).
// Block = 256 thr = 4 waves; 128 rows/block, 32 rows/wave.
// LDS B layout: 16B chunk index = ((ct*2+hs)*8+kc)*64 + lane, so each
// consumer ds_read_b128 is 1KB contiguous per wave (2 lanes/bank = free).
// Producer: thread t iter i covers (n = idx&127, c = idx>>7), coalesced-ish
// global reads, 2-way-only LDS write conflicts. One __syncthreads total.
// A-fragments from global (own rows, L1-resident). 64 MFMAs/wave.
// C/D: col=lane&31, row=(reg&3)+8*(reg>>2)+4*(lane>>5).
// ---------------------------------------------------------------------------
__global__ __launch_bounds__(256) void mfma32_kernel(
    const unsigned short* __restrict__ A16, const unsigned short* __restrict__ Msg16,
    const unsigned short* __restrict__ Wt,   // [128 n][256 k] bf16
    const float* __restrict__ bias,
    const float* __restrict__ ln_g, const float* __restrict__ ln_b,
    unsigned short* __restrict__ Out16, float* __restrict__ Out32,
    int N, int do_ln)
{
    __shared__ unsigned short sB[32768];   // 64 KB

    const int tid  = threadIdx.x;
    const int wave = tid >> 6;
    const int lane = tid & 63;
    const int half = lane >> 5;
    const int n32  = lane & 31;
    const int wrow0 = blockIdx.x * 128 + wave * 32;

    // ---- stage Wt -> LDS (swizzled) ----
#pragma unroll
    for (int i = 0; i < 16; i++) {
        int idx = tid + i * 256;          // 0..4095 (16B chunks)
        int n = idx & 127;
        int c = idx >> 7;                 // 0..31, k = c*8..c*8+7
        uint4 w = *(const uint4*)(Wt + (size_t)n * 256 + c * 8);
        int hs = c >> 4, kc = (c >> 1) & 7, hf = c & 1;
        int ct = n >> 5, nn = n & 31;
        int chunk = (((ct * 2 + hs) * 8 + kc) * 2 + hf) * 32 + nn;
        *(uint4*)&sB[(size_t)chunk * 8] = w;
    }
    __syncthreads();

    const int arow = wrow0 + n32;            // A row this lane feeds (m=lane&31)
    const bool arv = arow < N;
    const size_t koff = (size_t)half * 8;

    floatx16 acc[4];
#pragma unroll
    for (int ct = 0; ct < 4; ct++)
#pragma unroll
        for (int r = 0; r < 16; r++) acc[ct][r] = 0.f;

#pragma unroll
    for (int hs = 0; hs < 2; hs++) {
        const unsigned short* Asrc = hs ? Msg16 : A16;
#pragma unroll
        for (int kc = 0; kc < 8; kc++) {
            short8 a;
            if (arv) a = *(const short8*)(Asrc + (size_t)arow * D + kc * 16 + koff);
            else     a = (short8){0,0,0,0,0,0,0,0};
#pragma unroll
            for (int ct = 0; ct < 4; ct++) {
                short8 b = *(const short8*)&sB[((size_t)((ct * 2 + hs) * 8 + kc) * 64 + lane) * 8];
                acc[ct] = __builtin_amdgcn_mfma_f32_32x32x16_bf16(a, b, acc[ct], 0, 0, 0);
            }
        }
    }

    // ---- Epilogue ----
    float bb[4];
#pragma unroll
    for (int ct = 0; ct < 4; ct++) bb[ct] = bias[ct * 32 + n32];

    float v[4][16];
#pragma unroll
    for (int ct = 0; ct < 4; ct++)
#pragma unroll
        for (int r = 0; r < 16; r++) v[ct][r] = acc[ct][r] + bb[ct];

    if (do_ln) {
        float gg[4], be[4];
#pragma unroll
        for (int ct = 0; ct < 4; ct++) {
            gg[ct] = ln_g[ct * 32 + n32];
            be[ct] = ln_b[ct * 32 + n32];
        }
        float s[16], s2[16];
#pragma unroll
        for (int r = 0; r < 16; r++) {
            s[r]  = v[0][r] + v[1][r] + v[2][r] + v[3][r];
            s2[r] = v[0][r]*v[0][r] + v[1][r]*v[1][r] + v[2][r]*v[2][r] + v[3][r]*v[3][r];
        }
#pragma unroll
        for (int off = 1; off < 32; off <<= 1) {
#pragma unroll
            for (int r = 0; r < 16; r++) {
                s[r]  += __shfl_xor(s[r],  off);
                s2[r] += __shfl_xor(s2[r], off);
            }
        }
#pragma unroll
        for (int r = 0; r < 16; r++) {
            float mean = s[r] * (1.f / 128.f);
            float var  = s2[r] * (1.f / 128.f) - mean * mean;
            float rstd = rsqrtf(var + 1e-5f);
            int row_g = wrow0 + (r & 3) + 8 * (r >> 2) + 4 * half;
            if (row_g < N) {
#pragma unroll
                for (int ct = 0; ct < 4; ct++) {
                    float t = (v[ct][r] - mean) * rstd * gg[ct] + be[ct];
                    t = t > 0.f ? t : 0.f;
                    Out16[(size_t)row_g * D + ct * 32 + n32] = bf16_rne(t);
                }
            }
        }
    } else {
#pragma unroll
        for (int r = 0; r < 16; r++) {
            int row_g = wrow0 + (r & 3) + 8 * (r >> 2) + 4 * half;
            if (row_g < N) {
#pragma unroll
                for (int ct = 0; ct < 4; ct++)
                    Out32[(size_t)row_g * D + ct * 32 + n32] = v[ct][r];
            }
        }
    }
}

// ---------------------------------------------------------------------------
extern "C" void kernel_launch(void* const* d_in, const int* in_sizes, int n_in,
                              void* d_out, int out_size, void* d_ws, size_t ws_size,
                              hipStream_t stream)
{
    const float* feat = (const float*)d_in[0];
    const float* Ws0  = (const float*)d_in[1];
    const float* Wn0  = (const float*)d_in[2];
    const float* b0   = (const float*)d_in[3];
    const float* Ws1  = (const float*)d_in[4];
    const float* Wn1  = (const float*)d_in[5];
    const float* b1   = (const float*)d_in[6];
    const float* lng  = (const float*)d_in[7];
    const float* lnb  = (const float*)d_in[8];
    const int* esrc   = (const int*)d_in[9];
    const int* edst   = (const int*)d_in[10];
    const int* indeg  = (const int*)d_in[11];

    const int N = NN;
    const int E = in_sizes[9];

    float* out = (float*)d_out;

    // workspace: feat16 | col | row_ptr | wt0 | wt1 | bsums | boffs | D-region
    // D-region overlay: [counts + rank] (CSR build) then [h1_16] (compute)
    // msg ping-pong: layer0 msg -> d_out (bf16 scratch); layer1 msg -> feat16.
    char* ws = (char*)d_ws;
    size_t o = 0;
    auto alloc = [&](size_t bytes) { char* p = ws + o; o += (bytes + 15) & ~(size_t)15; return p; };
    unsigned short* feat16 = (unsigned short*)alloc((size_t)N * D * 2);
    int* col     = (int*)alloc((size_t)E * 4);
    int* row_ptr = (int*)alloc((size_t)(N + 1) * 4);
    unsigned short* wt0 = (unsigned short*)alloc(128 * 256 * 2);
    unsigned short* wt1 = (unsigned short*)alloc(128 * 256 * 2);
    int* bsums = (int*)alloc(1024);
    int* boffs = (int*)alloc(1024);
    char* regD = alloc((size_t)N * D * 2 > ((size_t)N * 4 + (size_t)E * 4 + 32)
                       ? (size_t)N * D * 2 : ((size_t)N * 4 + (size_t)E * 4 + 32));
    int* counts = (int*)regD;
    int* rank   = (int*)(regD + (((size_t)N * 4 + 15) & ~(size_t)15));
    unsigned short* h116 = (unsigned short*)regD;
    unsigned short* msg0 = (unsigned short*)d_out;
    unsigned short* msg1 = feat16;
    (void)ws_size;

    const int edge_blocks = (E + 255) / 256;
    const int gemm_blocks = (N + 127) / 128;
    const int gather_blocks = (N + 15) / 16;
    const int nb = (N + 1023) / 1024;
    const int zero_blocks = (N / 4 + 255) / 256;

    // --- fused prep: cvt feat->bf16, build Wt, zero counts ---
    prep_kernel<<<12500 + 256 + zero_blocks, 256, 0, stream>>>(
        feat, feat16, Ws0, Wn0, Ws1, Wn1, wt0, wt1, counts);

    // --- CSR build ---
    hist_rank_kernel<<<edge_blocks, 256, 0, stream>>>(edst, counts, rank, E);
    scan1_kernel<<<nb, 256, 0, stream>>>(counts, row_ptr, bsums, N);
    scan2_kernel<<<1, 256, 0, stream>>>(bsums, boffs, nb);
    scan3_kernel<<<(N + 256) / 256, 256, 0, stream>>>(row_ptr, boffs, N, E);
    fill_stream_kernel<<<edge_blocks, 256, 0, stream>>>(esrc, edst, row_ptr, rank, col, E);

    // --- Layer 0 ---
    gather16_kernel<<<gather_blocks, 256, 0, stream>>>(feat16, row_ptr, col, indeg, msg0, N);
    mfma32_kernel<<<gemm_blocks, 256, 0, stream>>>(
        feat16, msg0, wt0, b0, lng, lnb, h116, nullptr, N, 1);

    // --- Layer 1 ---
    gather16_kernel<<<gather_blocks, 256, 0, stream>>>(h116, row_ptr, col, indeg, msg1, N);
    mfma32_kernel<<<gemm_blocks, 256, 0, stream>>>(
        h116, msg1, wt1, b1, nullptr, nullptr, nullptr, out, N, 0);
}

// Round 8
// 371.825 us; speedup vs baseline: 1.3488x; 1.1531x over previous
//
#include <hip/hip_runtime.h>

#define D 128
#define NN 100000

typedef __attribute__((ext_vector_type(8))) short short8;
typedef __attribute__((ext_vector_type(16))) float floatx16;
typedef __attribute__((ext_vector_type(2))) float floatx2;

__device__ inline unsigned short bf16_rne(float f) {
    unsigned int u = __float_as_uint(f);
    u += 0x7fff + ((u >> 16) & 1);
    return (unsigned short)(u >> 16);
}
__device__ inline unsigned char fp8_enc1(float f) {
    return (unsigned char)(__builtin_amdgcn_cvt_pk_fp8_f32(f, f, 0, false) & 0xff);
}

// ---------------------------------------------------------------------------
// Fused prep: [0,12500) cvt feat->bf16+fp8 | [12500,12756) build Wt | rest zero counts
// ---------------------------------------------------------------------------
__global__ __launch_bounds__(256) void prep_kernel(
    const float* __restrict__ feat, unsigned short* __restrict__ feat16,
    unsigned char* __restrict__ feat8,
    const float* __restrict__ Ws0, const float* __restrict__ Wn0,
    const float* __restrict__ Ws1, const float* __restrict__ Wn1,
    unsigned short* __restrict__ wt0, unsigned short* __restrict__ wt1,
    int* __restrict__ counts)
{
    int bid = blockIdx.x;
    if (bid < 12500) {
        int i = bid * 256 + threadIdx.x;                 // float4 index
        float4 v = *(const float4*)(feat + (size_t)i * 4);
        unsigned short u[4] = { bf16_rne(v.x), bf16_rne(v.y), bf16_rne(v.z), bf16_rne(v.w) };
        *(uint2*)(feat16 + (size_t)i * 4) = *(uint2*)u;
        int w = __builtin_amdgcn_cvt_pk_fp8_f32(v.x, v.y, 0, false);
        w = __builtin_amdgcn_cvt_pk_fp8_f32(v.z, v.w, w, true);
        ((unsigned int*)feat8)[i] = (unsigned int)w;
    } else if (bid < 12756) {
        int i = (bid - 12500) * 256 + threadIdx.x;       // 0..65535
        int layer = i >> 15;
        int r = i & 32767;
        int n = r >> 8;
        int k = r & 255;
        const float* Ws = layer ? Ws1 : Ws0;
        const float* Wn = layer ? Wn1 : Wn0;
        float v = (k < 128) ? Ws[(size_t)k * 128 + n] : Wn[(size_t)(k - 128) * 128 + n];
        unsigned short* wt = layer ? wt1 : wt0;
        wt[(size_t)n * 256 + k] = bf16_rne(v);
    } else {
        int i = (bid - 12756) * 256 + threadIdx.x;       // uint4 index
        if (i < NN / 4) ((uint4*)counts)[i] = make_uint4(0u, 0u, 0u, 0u);
    }
}

// ---------------------------------------------------------------------------
// CSR build: hist (+rank) -> scan -> streaming fill (no atomics in fill)
// ---------------------------------------------------------------------------
__global__ __launch_bounds__(256) void hist_rank_kernel(
    const int* __restrict__ dst, int* __restrict__ counts,
    int* __restrict__ rank, int E)
{
    int e = blockIdx.x * 256 + threadIdx.x;
    if (e < E) rank[e] = atomicAdd(&counts[dst[e]], 1);
}

__global__ __launch_bounds__(256) void scan1_kernel(
    const int* __restrict__ counts, int* __restrict__ row_ptr,
    int* __restrict__ blockSums, int N)
{
    __shared__ int sd[256];
    int t = threadIdx.x;
    int base = blockIdx.x * 1024;
    int v[4]; int tot = 0;
#pragma unroll
    for (int i = 0; i < 4; i++) {
        int idx = base + t * 4 + i;
        v[i] = (idx < N) ? counts[idx] : 0;
        tot += v[i];
    }
    sd[t] = tot; __syncthreads();
    for (int off = 1; off < 256; off <<= 1) {
        int x = (t >= off) ? sd[t - off] : 0;
        __syncthreads();
        sd[t] += x;
        __syncthreads();
    }
    int excl = sd[t] - tot;
    if (t == 255) blockSums[blockIdx.x] = sd[255];
    int run = excl;
#pragma unroll
    for (int i = 0; i < 4; i++) {
        int idx = base + t * 4 + i;
        if (idx < N) row_ptr[idx] = run;
        run += v[i];
    }
}

__global__ __launch_bounds__(256) void scan2_kernel(
    const int* __restrict__ blockSums, int* __restrict__ blockOffs, int nb)
{
    __shared__ int sd[256];
    int t = threadIdx.x;
    int val = (t < nb) ? blockSums[t] : 0;
    sd[t] = val; __syncthreads();
    for (int off = 1; off < 256; off <<= 1) {
        int x = (t >= off) ? sd[t - off] : 0;
        __syncthreads();
        sd[t] += x;
        __syncthreads();
    }
    if (t < nb) blockOffs[t] = sd[t] - val;
}

__global__ __launch_bounds__(256) void scan3_kernel(
    int* __restrict__ row_ptr, const int* __restrict__ blockOffs, int N, int E)
{
    int i = blockIdx.x * 256 + threadIdx.x;
    if (i < N) row_ptr[i] += blockOffs[i >> 10];
    if (i == N) row_ptr[N] = E;
}

__global__ __launch_bounds__(256) void fill_stream_kernel(
    const int* __restrict__ src, const int* __restrict__ dst,
    const int* __restrict__ row_ptr, const int* __restrict__ rank,
    int* __restrict__ col, int E)
{
    int e = blockIdx.x * 256 + threadIdx.x;
    if (e >= E) return;
    col[row_ptr[dst[e]] + rank[e]] = src[e];
}

// ---------------------------------------------------------------------------
// Gather (fp8 table): msg16[node] = bf16( inv_deg * sum_j fp8row(col[j]) ).
// 16 lanes x uint2 (8 fp8 = 8B) per 128B row; 4 nodes per wave; 4-deep unroll.
// ---------------------------------------------------------------------------
__global__ __launch_bounds__(256) void gather8_kernel(
    const unsigned char* __restrict__ h8, const int* __restrict__ row_ptr,
    const int* __restrict__ col, const int* __restrict__ in_deg,
    unsigned short* __restrict__ msg16, int N)
{
    const int wave = threadIdx.x >> 6;
    const int lane = threadIdx.x & 63;
    const int quad = lane >> 4;
    const int ln16 = lane & 15;
    const int node = (blockIdx.x * 4 + wave) * 4 + quad;
    if (node >= N) return;

    const size_t lo = (size_t)ln16 * 8;   // byte offset within 128B row
    int beg = row_ptr[node];
    int end = row_ptr[node + 1];

    float f[8] = {0.f,0.f,0.f,0.f,0.f,0.f,0.f,0.f};
    int j = beg;
    for (; j + 4 <= end; j += 4) {
        int c0 = col[j], c1 = col[j + 1], c2 = col[j + 2], c3 = col[j + 3];
        uint2 u0 = *(const uint2*)(h8 + (size_t)c0 * D + lo);
        uint2 u1 = *(const uint2*)(h8 + (size_t)c1 * D + lo);
        uint2 u2 = *(const uint2*)(h8 + (size_t)c2 * D + lo);
        uint2 u3 = *(const uint2*)(h8 + (size_t)c3 * D + lo);
#pragma unroll
        for (int q = 0; q < 4; q++) {
            uint2 u = q == 0 ? u0 : q == 1 ? u1 : q == 2 ? u2 : u3;
            floatx2 p0 = __builtin_amdgcn_cvt_pk_f32_fp8((int)u.x, false);
            floatx2 p1 = __builtin_amdgcn_cvt_pk_f32_fp8((int)u.x, true);
            floatx2 p2 = __builtin_amdgcn_cvt_pk_f32_fp8((int)u.y, false);
            floatx2 p3 = __builtin_amdgcn_cvt_pk_f32_fp8((int)u.y, true);
            f[0] += p0.x; f[1] += p0.y; f[2] += p1.x; f[3] += p1.y;
            f[4] += p2.x; f[5] += p2.y; f[6] += p3.x; f[7] += p3.y;
        }
    }
    for (; j < end; ++j) {
        uint2 u = *(const uint2*)(h8 + (size_t)col[j] * D + lo);
        floatx2 p0 = __builtin_amdgcn_cvt_pk_f32_fp8((int)u.x, false);
        floatx2 p1 = __builtin_amdgcn_cvt_pk_f32_fp8((int)u.x, true);
        floatx2 p2 = __builtin_amdgcn_cvt_pk_f32_fp8((int)u.y, false);
        floatx2 p3 = __builtin_amdgcn_cvt_pk_f32_fp8((int)u.y, true);
        f[0] += p0.x; f[1] += p0.y; f[2] += p1.x; f[3] += p1.y;
        f[4] += p2.x; f[5] += p2.y; f[6] += p3.x; f[7] += p3.y;
    }
    int dg = in_deg[node];
    float invd = 1.f / (float)(dg > 1 ? dg : 1);
    unsigned short us[8];
#pragma unroll
    for (int i = 0; i < 8; i++) us[i] = bf16_rne(f[i] * invd);
    *(uint4*)(msg16 + (size_t)node * D + ln16 * 8) = *(const uint4*)us;
}

// ---------------------------------------------------------------------------
// MFMA dual-GEMM 32x32x16_bf16, B staged in LDS (64KB, one barrier).
// Block = 256 thr = 4 waves; 128 rows/block, 32 rows/wave.
// C/D: col=lane&31, row=(reg&3)+8*(reg>>2)+4*(lane>>5).
// do_ln: writes Out16 (bf16, GEMM self input) AND Out8 (fp8, gather table).
// ---------------------------------------------------------------------------
__global__ __launch_bounds__(256) void mfma32_kernel(
    const unsigned short* __restrict__ A16, const unsigned short* __restrict__ Msg16,
    const unsigned short* __restrict__ Wt,   // [128 n][256 k] bf16
    const float* __restrict__ bias,
    const float* __restrict__ ln_g, const float* __restrict__ ln_b,
    unsigned short* __restrict__ Out16, unsigned char* __restrict__ Out8,
    float* __restrict__ Out32, int N, int do_ln)
{
    __shared__ unsigned short sB[32768];   // 64 KB

    const int tid  = threadIdx.x;
    const int wave = tid >> 6;
    const int lane = tid & 63;
    const int half = lane >> 5;
    const int n32  = lane & 31;
    const int wrow0 = blockIdx.x * 128 + wave * 32;

    // ---- stage Wt -> LDS (swizzled) ----
#pragma unroll
    for (int i = 0; i < 16; i++) {
        int idx = tid + i * 256;          // 0..4095 (16B chunks)
        int n = idx & 127;
        int c = idx >> 7;                 // 0..31, k = c*8..c*8+7
        uint4 w = *(const uint4*)(Wt + (size_t)n * 256 + c * 8);
        int hs = c >> 4, kc = (c >> 1) & 7, hf = c & 1;
        int ct = n >> 5, nn = n & 31;
        int chunk = (((ct * 2 + hs) * 8 + kc) * 2 + hf) * 32 + nn;
        *(uint4*)&sB[(size_t)chunk * 8] = w;
    }
    __syncthreads();

    const int arow = wrow0 + n32;
    const bool arv = arow < N;
    const size_t koff = (size_t)half * 8;

    floatx16 acc[4];
#pragma unroll
    for (int ct = 0; ct < 4; ct++)
#pragma unroll
        for (int r = 0; r < 16; r++) acc[ct][r] = 0.f;

#pragma unroll
    for (int hs = 0; hs < 2; hs++) {
        const unsigned short* Asrc = hs ? Msg16 : A16;
#pragma unroll
        for (int kc = 0; kc < 8; kc++) {
            short8 a;
            if (arv) a = *(const short8*)(Asrc + (size_t)arow * D + kc * 16 + koff);
            else     a = (short8){0,0,0,0,0,0,0,0};
#pragma unroll
            for (int ct = 0; ct < 4; ct++) {
                short8 b = *(const short8*)&sB[((size_t)((ct * 2 + hs) * 8 + kc) * 64 + lane) * 8];
                acc[ct] = __builtin_amdgcn_mfma_f32_32x32x16_bf16(a, b, acc[ct], 0, 0, 0);
            }
        }
    }

    // ---- Epilogue ----
    float bb[4];
#pragma unroll
    for (int ct = 0; ct < 4; ct++) bb[ct] = bias[ct * 32 + n32];

    float v[4][16];
#pragma unroll
    for (int ct = 0; ct < 4; ct++)
#pragma unroll
        for (int r = 0; r < 16; r++) v[ct][r] = acc[ct][r] + bb[ct];

    if (do_ln) {
        float gg[4], be[4];
#pragma unroll
        for (int ct = 0; ct < 4; ct++) {
            gg[ct] = ln_g[ct * 32 + n32];
            be[ct] = ln_b[ct * 32 + n32];
        }
        float s[16], s2[16];
#pragma unroll
        for (int r = 0; r < 16; r++) {
            s[r]  = v[0][r] + v[1][r] + v[2][r] + v[3][r];
            s2[r] = v[0][r]*v[0][r] + v[1][r]*v[1][r] + v[2][r]*v[2][r] + v[3][r]*v[3][r];
        }
#pragma unroll
        for (int off = 1; off < 32; off <<= 1) {
#pragma unroll
            for (int r = 0; r < 16; r++) {
                s[r]  += __shfl_xor(s[r],  off);
                s2[r] += __shfl_xor(s2[r], off);
            }
        }
#pragma unroll
        for (int r = 0; r < 16; r++) {
            float mean = s[r] * (1.f / 128.f);
            float var  = s2[r] * (1.f / 128.f) - mean * mean;
            float rstd = rsqrtf(var + 1e-5f);
            int row_g = wrow0 + (r & 3) + 8 * (r >> 2) + 4 * half;
            if (row_g < N) {
#pragma unroll
                for (int ct = 0; ct < 4; ct++) {
                    float t = (v[ct][r] - mean) * rstd * gg[ct] + be[ct];
                    t = t > 0.f ? t : 0.f;
                    Out16[(size_t)row_g * D + ct * 32 + n32] = bf16_rne(t);
                    Out8[(size_t)row_g * D + ct * 32 + n32] = fp8_enc1(t);
                }
            }
        }
    } else {
#pragma unroll
        for (int r = 0; r < 16; r++) {
            int row_g = wrow0 + (r & 3) + 8 * (r >> 2) + 4 * half;
            if (row_g < N) {
#pragma unroll
                for (int ct = 0; ct < 4; ct++)
                    Out32[(size_t)row_g * D + ct * 32 + n32] = v[ct][r];
            }
        }
    }
}

// ---------------------------------------------------------------------------
extern "C" void kernel_launch(void* const* d_in, const int* in_sizes, int n_in,
                              void* d_out, int out_size, void* d_ws, size_t ws_size,
                              hipStream_t stream)
{
    const float* feat = (const float*)d_in[0];
    const float* Ws0  = (const float*)d_in[1];
    const float* Wn0  = (const float*)d_in[2];
    const float* b0   = (const float*)d_in[3];
    const float* Ws1  = (const float*)d_in[4];
    const float* Wn1  = (const float*)d_in[5];
    const float* b1   = (const float*)d_in[6];
    const float* lng  = (const float*)d_in[7];
    const float* lnb  = (const float*)d_in[8];
    const int* esrc   = (const int*)d_in[9];
    const int* edst   = (const int*)d_in[10];
    const int* indeg  = (const int*)d_in[11];

    const int N = NN;
    const int E = in_sizes[9];

    float* out = (float*)d_out;

    // ws: feat16 | col | row_ptr | wt0 | wt1 | bsums | boffs | D-region
    //   D-region overlay: [counts + rank] (CSR build) then [h1_16] (compute)
    // d_out overlay (51.2MB, dead until final write):
    //   [0, 25.6M):     msg0 (bf16, layer-0 msg)
    //   [25.6M, 38.4M): feat8 (fp8 table, layer-0 gather input)
    //   [38.4M, 51.2M): h18  (fp8 table, layer-1 gather input)
    // msg1 -> feat16 region (dead after layer 0).
    char* ws = (char*)d_ws;
    size_t o = 0;
    auto alloc = [&](size_t bytes) { char* p = ws + o; o += (bytes + 15) & ~(size_t)15; return p; };
    unsigned short* feat16 = (unsigned short*)alloc((size_t)N * D * 2);
    int* col     = (int*)alloc((size_t)E * 4);
    int* row_ptr = (int*)alloc((size_t)(N + 1) * 4);
    unsigned short* wt0 = (unsigned short*)alloc(128 * 256 * 2);
    unsigned short* wt1 = (unsigned short*)alloc(128 * 256 * 2);
    int* bsums = (int*)alloc(1024);
    int* boffs = (int*)alloc(1024);
    char* regD = alloc((size_t)N * D * 2 > ((size_t)N * 4 + (size_t)E * 4 + 32)
                       ? (size_t)N * D * 2 : ((size_t)N * 4 + (size_t)E * 4 + 32));
    int* counts = (int*)regD;
    int* rank   = (int*)(regD + (((size_t)N * 4 + 15) & ~(size_t)15));
    unsigned short* h116 = (unsigned short*)regD;

    unsigned short* msg0 = (unsigned short*)d_out;
    unsigned char*  feat8 = (unsigned char*)d_out + (size_t)N * D * 2;
    unsigned char*  h18   = (unsigned char*)d_out + (size_t)N * D * 3;
    unsigned short* msg1 = feat16;
    (void)ws_size;

    const int edge_blocks = (E + 255) / 256;
    const int gemm_blocks = (N + 127) / 128;
    const int gather_blocks = (N + 15) / 16;
    const int nb = (N + 1023) / 1024;
    const int zero_blocks = (N / 4 + 255) / 256;

    // --- fused prep: cvt feat->bf16+fp8, build Wt, zero counts ---
    prep_kernel<<<12500 + 256 + zero_blocks, 256, 0, stream>>>(
        feat, feat16, feat8, Ws0, Wn0, Ws1, Wn1, wt0, wt1, counts);

    // --- CSR build ---
    hist_rank_kernel<<<edge_blocks, 256, 0, stream>>>(edst, counts, rank, E);
    scan1_kernel<<<nb, 256, 0, stream>>>(counts, row_ptr, bsums, N);
    scan2_kernel<<<1, 256, 0, stream>>>(bsums, boffs, nb);
    scan3_kernel<<<(N + 256) / 256, 256, 0, stream>>>(row_ptr, boffs, N, E);
    fill_stream_kernel<<<edge_blocks, 256, 0, stream>>>(esrc, edst, row_ptr, rank, col, E);

    // --- Layer 0 ---
    gather8_kernel<<<gather_blocks, 256, 0, stream>>>(feat8, row_ptr, col, indeg, msg0, N);
    mfma32_kernel<<<gemm_blocks, 256, 0, stream>>>(
        feat16, msg0, wt0, b0, lng, lnb, h116, h18, nullptr, N, 1);

    // --- Layer 1 ---
    gather8_kernel<<<gather_blocks, 256, 0, stream>>>(h18, row_ptr, col, indeg, msg1, N);
    mfma32_kernel<<<gemm_blocks, 256, 0, stream>>>(
        h116, msg1, wt1, b1, nullptr, nullptr, nullptr, nullptr, out, N, 0);
}